// Round 5
// baseline (976.721 us; speedup 1.0000x reference)
//
#include <hip/hip_runtime.h>

#define PS 7
#define NP 10
#define WIN 20
#define STR 4
#define LL 14          // WIN - PS + 1
#define HALF 7
#define HH 160
#define WW 160
#define BCN 32         // B*C
#define NX 36          // positions per axis
#define PPOS 1296      // NX*NX
#define EMBD 128
#define NTASK (BCN * PPOS * NP)   // 414720
#define NEV (PPOS * NP)           // 12960 events per plane
#define CAP 2048                  // per-tile event list capacity
#define NTILE 100                 // 10x10 tiles of 16x16 per plane

// ---------------- phase 0: M = Wp@Wb, K[n] = (bp+pos_emb[n])@Wb + bb ---------
__global__ __launch_bounds__(256) void k_mk(const float* __restrict__ Wp,
                                            const float* __restrict__ bp,
                                            const float* __restrict__ pe,
                                            const float* __restrict__ Wb,
                                            const float* __restrict__ bb,
                                            float* __restrict__ M,
                                            float* __restrict__ K) {
    int t = blockIdx.x * 256 + threadIdx.x;
    if (t < 49 * 49) {
        int k = t / 49, d = t % 49;
        float acc = 0.f;
        for (int e = 0; e < EMBD; ++e) acc += Wp[k * EMBD + e] * Wb[e * 49 + d];
        M[t] = acc;
    } else if (t < 49 * 49 + NP * 49) {
        int u = t - 49 * 49;
        int n = u / 49, d = u % 49;
        float acc = bb[d];
        for (int e = 0; e < EMBD; ++e) acc += (bp[e] + pe[n * EMBD + e]) * Wb[e * 49 + d];
        K[u] = acc;
    }
}

// ---------------- phase 1: sim + top-10 + patch extraction -------------------
// block = 256 threads = 4 waves = 4 consecutive iy positions sharing one ix.
// Their 20x20 windows overlap; stage the union (<=32 rows x 20 cols) in LDS.
__global__ __launch_bounds__(256) void k_sim(const float* __restrict__ img,
                                             unsigned* __restrict__ xy,
                                             float* __restrict__ pd) {
    int blk = blockIdx.x;              // blk = (bc*NX + ix)*9 + iyg
    int iyg = blk % 9;
    int rem = blk / 9;
    int ix  = rem % NX;
    int bc  = rem / NX;
    int tid  = threadIdx.x;
    int wv   = tid >> 6;
    int lane = tid & 63;

    int x = ix * STR, xb0 = max(x - HALF, 0);
    int iy = iyg * 4 + wv;
    int y = iy * STR, yb0 = max(y - HALF, 0);
    int y0g = max(iyg * 16 - HALF, 0);     // first wave's yb0 == group row base
    const float* plane = img + bc * (HH * WW);

    __shared__ float win[32 * 22];         // rows y0g..y0g+31, cols xb0..+19, stride 22
    for (int i = tid; i < 640; i += 256) {
        int rr = i / 20, ccc = i % 20;
        win[rr * 22 + ccc] = plane[(y0g + rr) * WW + xb0 + ccc];
    }
    __syncthreads();

    int li = yb0 - y0g;                    // wave's window-row offset in LDS [0,12]
    int jmax = x + 6 - xb0;                // valid j <= jmax
    int imax = y + 6 - yb0;

    // ref patch rows y..y+6, cols x..x+6 (subset of staged region) -> VGPRs
    int refr = y - y0g, refc = x - xb0;
    float rf[49];
#pragma unroll
    for (int a = 0; a < PS; ++a)
#pragma unroll
        for (int b = 0; b < PS; ++b)
            rf[a * 7 + b] = win[(refr + a) * 22 + refc + b];  // uniform -> broadcast

    float v[4];
    int   qi[4];
#pragma unroll
    for (int s = 0; s < 4; ++s) {
        int q = lane + s * 64;
        qi[s] = q;
        float acc = -INFINITY;
        if (q < 196) {
            int i = q / 14, j = q % 14;
            const float* wb = &win[(li + i) * 22 + j];
            float a2 = 0.f;
#pragma unroll
            for (int a = 0; a < PS; ++a)
#pragma unroll
                for (int b = 0; b < PS; ++b)
                    a2 += wb[a * 22 + b] * rf[a * 7 + b];
            acc = (i > imax || j > jmax) ? -INFINITY : a2;
        }
        v[s] = acc;
    }

    int pos = ix * NX + iy;
    int tbase = (bc * PPOS + pos) * NP;
    for (int n = 0; n < NP; ++n) {
        // local best (value desc, index asc)
        float bv = v[0]; int bi = qi[0];
#pragma unroll
        for (int s = 1; s < 4; ++s)
            if (v[s] > bv || (v[s] == bv && qi[s] < bi)) { bv = v[s]; bi = qi[s]; }
#pragma unroll
        for (int off = 32; off >= 1; off >>= 1) {
            float ov = __shfl_xor(bv, off);
            int   oi = __shfl_xor(bi, off);
            if (ov > bv || (ov == bv && oi < bi)) { bv = ov; bi = oi; }
        }
#pragma unroll
        for (int s = 0; s < 4; ++s)
            if (qi[s] == bi) v[s] = -INFINITY;

        int oy = bi / 14, ox = bi % 14;
        int x_i = oy + xb0;        // source bug kept: col start = row off + xb0
        int y_i = ox + yb0;        // row start = col off + yb0
        int t = tbase + n;
        if (lane == 0) xy[t] = (unsigned)x_i | ((unsigned)y_i << 8);
        if (lane < 49) {
            int a = lane / 7, b = lane % 7;     // patch[a*7+b] = win[oy+b][ox+a]
            pd[(size_t)t * 49 + lane] = win[(li + oy + b) * 22 + ox + a];
        }
    }
}

// ---------------- phase 2: den = patches @ M + K[n]  (in-place over pd) ------
__global__ __launch_bounds__(256) void k_den(float* __restrict__ pd,
                                             const float* __restrict__ Mg,
                                             const float* __restrict__ Kg) {
    __shared__ float Ps[256 * 49];
    int tid = threadIdx.x;
    size_t base = (size_t)blockIdx.x * (256 * 49);
    for (int i = tid; i < 256 * 49; i += 256) Ps[i] = pd[base + i];
    __syncthreads();

    int t = blockIdx.x * 256 + tid;
    int n = t % NP;
    float acc[49];
#pragma unroll
    for (int d = 0; d < 49; ++d) acc[d] = Kg[n * 49 + d];
    for (int k = 0; k < 49; ++k) {
        float p = Ps[tid * 49 + k];
        const float* mrow = Mg + k * 49;   // wave-uniform -> scalar loads
#pragma unroll
        for (int d = 0; d < 49; ++d) acc[d] += p * mrow[d];
    }
    __syncthreads();
#pragma unroll
    for (int d = 0; d < 49; ++d) Ps[tid * 49 + d] = acc[d];
    __syncthreads();
    for (int i = tid; i < 256 * 49; i += 256) pd[base + i] = Ps[i];
}

// ---------------- phase 3a: per-tile event-list build (order-preserving) -----
__global__ __launch_bounds__(64) void k_build(const unsigned* __restrict__ xy,
                                              unsigned* __restrict__ lists,
                                              unsigned* __restrict__ counts) {
    int blk  = blockIdx.x;
    int bc   = blk / NTILE;
    int tile = blk % NTILE;
    int tx0 = (tile % 10) * 16, ty0 = (tile / 10) * 16;
    int tx1 = tx0 + 15, ty1 = ty0 + 15;
    int lane = threadIdx.x;
    const unsigned* xs = xy + bc * NEV;
    unsigned* lst = lists + (size_t)blk * CAP;

    unsigned cnt = 0;
    for (int base = 0; base < NEV; base += 64) {
        int e = base + lane;
        bool valid = e < NEV;
        unsigned u = valid ? xs[e] : 0u;
        int x_i = (int)(u & 255u);
        int y_i = (int)((u >> 8) & 255u);
        bool ih = valid && (x_i <= tx1) && (x_i + 6 >= tx0) &&
                           (y_i <= ty1) && (y_i + 6 >= ty0);
        bool ch = valid && (x_i <= ty1) && (x_i + 6 >= ty0) &&
                           (y_i <= tx1) && (y_i + 6 >= tx0);
        bool any = ih || ch;
        unsigned long long m = __ballot(any);
        if (any) {
            unsigned pfx = (unsigned)__popcll(m & ((1ull << lane) - 1ull));
            unsigned slot = cnt + pfx;
            if (slot < CAP)
                lst[slot] = (unsigned)e | ((unsigned)x_i << 14) | ((unsigned)y_i << 22)
                          | (ih ? (1u << 30) : 0u) | (ch ? (1u << 31) : 0u);
        }
        cnt += (unsigned)__popcll(m);
    }
    if (cnt > CAP) cnt = CAP;
    unsigned cntp = (cnt + 7u) & ~7u;
    if (lane < (int)(cntp - cnt)) lst[cnt + lane] = 0u;   // zero-pad (no-op events)
    if (lane == 0) counts[blk] = cntp;
}

// ---------------- phase 3b: replay compact list ------------------------------
// Batch-of-8 unconditional event+d loads (round-4 pipeline, pinned with asm
// barriers), then per-event WAVE-UNIFORM SALU skip branches: each wave owns a
// 4x16 row band; irrelevant events cost only scalar work.
__global__ __launch_bounds__(256) void k_apply(const float* __restrict__ img,
                                               const unsigned* __restrict__ lists,
                                               const unsigned* __restrict__ counts,
                                               const float* __restrict__ pd,
                                               float* __restrict__ out) {
    int blk  = blockIdx.x;
    int bc   = blk / NTILE;
    int tile = blk % NTILE;
    int tx0 = (tile % 10) * 16, ty0 = (tile / 10) * 16;
    int tx1 = tx0 + 15;
    int tid = threadIdx.x;
    int r  = ty0 + (tid >> 4);
    int cc = tx0 + (tid & 15);
    int wv  = __builtin_amdgcn_readfirstlane(tid >> 6);
    int qr0 = ty0 + wv * 4;            // this wave's rows [qr0, qr0+3]

    float im = img[bc * (HH * WW) + r * WW + cc];
    float c  = 1.0f;
    const unsigned* lst = lists + (size_t)blk * CAP;
    const float*    ds  = pd + (size_t)bc * ((size_t)NEV * 49);
    int cnt = (int)counts[blk];
    int vOff = (r * 7 + cc) * 4;       // per-lane byte offset base 4*(7r+cc)

    for (int i = 0; i < cnt; i += 8) {
        unsigned eu[8];
        float    dv[8];
#pragma unroll
        for (int j = 0; j < 8; ++j)
            eu[j] = (unsigned)__builtin_amdgcn_readfirstlane((int)lst[i + j]);
#pragma unroll
        for (int j = 0; j < 8; ++j) {
            unsigned u = eu[j];                       // SGPR
            int t    = (int)(u & 16383u);             // SALU decode
            int x_i  = (int)((u >> 14) & 255u);
            int y_i  = (int)((u >> 22) & 255u);
            int sOff = (y_i * 7 + x_i) * 4;           // SALU
            const char* dsb = (const char*)(ds + (size_t)t * 49);
            int boc = min(max(vOff - sOff, 0), 192);  // v_sub + v_med3
            dv[j] = *(const float*)(dsb + boc);       // unconditional batched load
            asm volatile("" : "+v"(dv[j]));           // pin load above branches
        }
#pragma unroll
        for (int j = 0; j < 8; ++j) {
            unsigned u = eu[j];
            int x_i = (int)((u >> 14) & 255u);        // SALU
            int y_i = (int)((u >> 22) & 255u);
            // wave-uniform relevance for rows [qr0,qr0+3] x cols [tx0,tx1]
            bool imgRel = (u & (1u << 30)) &&
                          (y_i >= qr0 - 6) && (y_i <= qr0 + 3) &&
                          (x_i >= tx0 - 6) && (x_i <= tx1);
            bool cntRel = (u >> 31) &&
                          (x_i >= qr0 - 6) && (x_i <= qr0 + 3) &&
                          (y_i >= tx0 - 6) && (y_i <= tx1);
            if (imgRel) {   // image update first (reads pre-increment count)
                int bo = vOff - (y_i * 7 + x_i) * 4;
                // bo in [0,192] && dc in [0,6]  <=>  dr,dc both in [0,6]
                bool h = ((unsigned)bo <= 192u) & ((unsigned)(cc - x_i) <= 6u);
                float nim = fmaf(im, c, dv[j]) * __builtin_amdgcn_rcpf(c + 1.0f);
                im = h ? nim : im;
            }
            if (cntRel) {   // counter at transposed slice (source bug)
                int bo2 = vOff - (x_i * 7 + y_i) * 4;
                bool hc = ((unsigned)bo2 <= 192u) & ((unsigned)(cc - y_i) <= 6u);
                c += hc ? 1.0f : 0.0f;
            }
        }
    }
    out[bc * (HH * WW) + r * WW + cc] = im;
}

extern "C" void kernel_launch(void* const* d_in, const int* in_sizes, int n_in,
                              void* d_out, int out_size, void* d_ws, size_t ws_size,
                              hipStream_t stream) {
    const float* img = (const float*)d_in[0];
    const float* Wp  = (const float*)d_in[1];
    const float* bp  = (const float*)d_in[2];
    const float* pe  = (const float*)d_in[3];
    const float* Wb  = (const float*)d_in[4];
    const float* bb  = (const float*)d_in[5];
    float* out = (float*)d_out;

    float* wsf = (float*)d_ws;
    float*    M   = wsf;                        // 2401 floats (pad to 2404)
    float*    K   = wsf + 2404;                 // 490  floats (pad to 492)
    unsigned* xy  = (unsigned*)(wsf + 2896);    // 414720 u32
    float*    pd  = wsf + 2896 + NTASK;         // 20,321,280 floats
    unsigned* lists  = (unsigned*)(pd + (size_t)NTASK * 49);   // 3200*CAP u32
    unsigned* counts = lists + (size_t)BCN * NTILE * CAP;      // 3200 u32

    k_mk<<<12, 256, 0, stream>>>(Wp, bp, pe, Wb, bb, M, K);
    k_sim<<<BCN * NX * 9, 256, 0, stream>>>(img, xy, pd);
    k_den<<<NTASK / 256, 256, 0, stream>>>(pd, M, K);
    k_build<<<BCN * NTILE, 64, 0, stream>>>(xy, lists, counts);
    k_apply<<<BCN * NTILE, 256, 0, stream>>>(img, lists, counts, pd, out);
}

// Round 6
// 503.114 us; speedup vs baseline: 1.9414x; 1.9414x over previous
//
#include <hip/hip_runtime.h>

#define PS 7
#define NP 10
#define WIN 20
#define STR 4
#define LL 14          // WIN - PS + 1
#define HALF 7
#define HH 160
#define WW 160
#define BCN 32         // B*C
#define NX 36          // positions per axis
#define PPOS 1296      // NX*NX
#define EMBD 128
#define NTASK (BCN * PPOS * NP)   // 414720
#define NEV (PPOS * NP)           // 12960 events per plane
#define CAP 512                   // per-tile event list capacity (8x8 tiles)
#define NTILE 400                 // 20x20 tiles of 8x8 per plane

// ---------------- phase 0: M = Wp@Wb, K[n] = (bp+pos_emb[n])@Wb + bb ---------
__global__ __launch_bounds__(256) void k_mk(const float* __restrict__ Wp,
                                            const float* __restrict__ bp,
                                            const float* __restrict__ pe,
                                            const float* __restrict__ Wb,
                                            const float* __restrict__ bb,
                                            float* __restrict__ M,
                                            float* __restrict__ K) {
    int t = blockIdx.x * 256 + threadIdx.x;
    if (t < 49 * 49) {
        int k = t / 49, d = t % 49;
        float acc = 0.f;
        for (int e = 0; e < EMBD; ++e) acc += Wp[k * EMBD + e] * Wb[e * 49 + d];
        M[t] = acc;
    } else if (t < 49 * 49 + NP * 49) {
        int u = t - 49 * 49;
        int n = u / 49, d = u % 49;
        float acc = bb[d];
        for (int e = 0; e < EMBD; ++e) acc += (bp[e] + pe[n * EMBD + e]) * Wb[e * 49 + d];
        K[u] = acc;
    }
}

// ---------------- phase 1: sim + top-10 + patch extraction (round-4 proven) --
// one wave per (pos, bc). layout: t = (bc*PPOS + pos)*NP + n
__global__ __launch_bounds__(64) void k_sim(const float* __restrict__ img,
                                            unsigned* __restrict__ xy,
                                            float* __restrict__ pd) {
    int blk = blockIdx.x;
    int pos = blk % PPOS;
    int bc  = blk / PPOS;
    int lane = threadIdx.x;
    int ix = pos / NX, iy = pos % NX;
    int x = ix * STR, y = iy * STR;
    int xb0 = max(x - HALF, 0), yb0 = max(y - HALF, 0);
    int jmax = x + 6 - xb0;   // valid j <= jmax  (==13 when x>=7)
    int imax = y + 6 - yb0;
    const float* plane = img + bc * (HH * WW);

    float v[4];
    int   qi[4];
#pragma unroll
    for (int s = 0; s < 4; ++s) {
        int q = lane + s * 64;
        qi[s] = q;
        float acc = -INFINITY;
        if (q < 196) {
            int i = q / 14, j = q % 14;
            const float* wbase = plane + (yb0 + i) * WW + (xb0 + j);
            float a2 = 0.f;
#pragma unroll
            for (int a = 0; a < PS; ++a)
#pragma unroll
                for (int b = 0; b < PS; ++b)
                    a2 += wbase[a * WW + b] * plane[(y + a) * WW + (x + b)];
            acc = (i > imax || j > jmax) ? -INFINITY : a2;
        }
        v[s] = acc;
    }

    int tbase = (bc * PPOS + pos) * NP;
    for (int n = 0; n < NP; ++n) {
        // local best (value desc, index asc)
        float bv = v[0]; int bi = qi[0];
#pragma unroll
        for (int s = 1; s < 4; ++s)
            if (v[s] > bv || (v[s] == bv && qi[s] < bi)) { bv = v[s]; bi = qi[s]; }
        // wave butterfly argmax — associative lexicographic max on (val, -idx)
#pragma unroll
        for (int off = 32; off >= 1; off >>= 1) {
            float ov = __shfl_xor(bv, off);
            int   oi = __shfl_xor(bi, off);
            if (ov > bv || (ov == bv && oi < bi)) { bv = ov; bi = oi; }
        }
        // remove winner
#pragma unroll
        for (int s = 0; s < 4; ++s)
            if (qi[s] == bi) v[s] = -INFINITY;

        int oy = bi / 14, ox = bi % 14;
        int x_i = oy + xb0;        // source bug kept: col start = row off + xb0
        int y_i = ox + yb0;        // row start = col off + yb0
        int row0 = yb0 + oy, col0 = xb0 + ox;
        int t = tbase + n;
        if (lane == 0) xy[t] = (unsigned)x_i | ((unsigned)y_i << 8);
        if (lane < 49) {
            int a = lane / 7, b = lane % 7;     // patch[a*7+b] = win[oy+b][ox+a]
            pd[(size_t)t * 49 + lane] = plane[(row0 + b) * WW + (col0 + a)];
        }
    }
}

// ---------------- phase 2: den = patches @ M + K[n]  (in-place over pd) ------
__global__ __launch_bounds__(256) void k_den(float* __restrict__ pd,
                                             const float* __restrict__ Mg,
                                             const float* __restrict__ Kg) {
    __shared__ float Ps[256 * 49];
    int tid = threadIdx.x;
    size_t base = (size_t)blockIdx.x * (256 * 49);
    for (int i = tid; i < 256 * 49; i += 256) Ps[i] = pd[base + i];
    __syncthreads();

    int t = blockIdx.x * 256 + tid;
    int n = t % NP;
    float acc[49];
#pragma unroll
    for (int d = 0; d < 49; ++d) acc[d] = Kg[n * 49 + d];
    for (int k = 0; k < 49; ++k) {
        float p = Ps[tid * 49 + k];
        const float* mrow = Mg + k * 49;   // wave-uniform -> scalar loads
#pragma unroll
        for (int d = 0; d < 49; ++d) acc[d] += p * mrow[d];
    }
    __syncthreads();
#pragma unroll
    for (int d = 0; d < 49; ++d) Ps[tid * 49 + d] = acc[d];
    __syncthreads();
    for (int i = tid; i < 256 * 49; i += 256) pd[base + i] = Ps[i];
}

// ---------------- phase 3a: per-tile (8x8) event-list build ------------------
// one wave per (bc, tile). Event e = pos*NP + n; chronological order == e order.
// Packed event u32: t(14b) | x_i<<14 (8b) | y_i<<22 (8b) | ih<<30 | ch<<31.
// Zero-padded to a multiple of 8 (zero event is a no-op: flags = 0).
__global__ __launch_bounds__(64) void k_build(const unsigned* __restrict__ xy,
                                              unsigned* __restrict__ lists,
                                              unsigned* __restrict__ counts) {
    int blk  = blockIdx.x;
    int bc   = blk / NTILE;
    int tile = blk % NTILE;
    int tx0 = (tile % 20) * 8, ty0 = (tile / 20) * 8;
    int tx1 = tx0 + 7, ty1 = ty0 + 7;
    int lane = threadIdx.x;
    const unsigned* xs = xy + bc * NEV;
    unsigned* lst = lists + (size_t)blk * CAP;

    unsigned cnt = 0;
    for (int base = 0; base < NEV; base += 64) {
        int e = base + lane;
        bool valid = e < NEV;
        unsigned u = valid ? xs[e] : 0u;
        int x_i = (int)(u & 255u);
        int y_i = (int)((u >> 8) & 255u);
        // image region rows [y_i, y_i+6], cols [x_i, x_i+6]
        bool ih = valid && (x_i <= tx1) && (x_i + 6 >= tx0) &&
                           (y_i <= ty1) && (y_i + 6 >= ty0);
        // counter region rows [x_i, x_i+6], cols [y_i, y_i+6]  (source bug)
        bool ch = valid && (x_i <= ty1) && (x_i + 6 >= ty0) &&
                           (y_i <= tx1) && (y_i + 6 >= tx0);
        bool any = ih || ch;
        unsigned long long m = __ballot(any);
        if (any) {
            unsigned pfx = (unsigned)__popcll(m & ((1ull << lane) - 1ull));
            unsigned slot = cnt + pfx;
            if (slot < CAP)
                lst[slot] = (unsigned)e | ((unsigned)x_i << 14) | ((unsigned)y_i << 22)
                          | (ih ? (1u << 30) : 0u) | (ch ? (1u << 31) : 0u);
        }
        cnt += (unsigned)__popcll(m);
    }
    if (cnt > CAP) cnt = CAP;
    unsigned cntp = (cnt + 7u) & ~7u;
    if (cntp > CAP) cntp = CAP;
    if (lane < (int)(cntp - cnt)) lst[cnt + lane] = 0u;   // zero-pad (no-op events)
    if (lane == 0) counts[blk] = cntp;
}

// ---------------- phase 3b: replay compact list, one WAVE per 8x8 tile -------
// Round-4 proven inner loop verbatim (batch-of-8, scalarized decode, pure
// predication, NO branches). 8x8 tiles cut wave-events/event 7.6 -> 3.06.
__global__ __launch_bounds__(64) void k_apply(const float* __restrict__ img,
                                              const unsigned* __restrict__ lists,
                                              const unsigned* __restrict__ counts,
                                              const float* __restrict__ pd,
                                              float* __restrict__ out) {
    int blk  = blockIdx.x;
    int bc   = blk / NTILE;
    int tile = blk % NTILE;
    int tx0 = (tile % 20) * 8, ty0 = (tile / 20) * 8;
    int lane = threadIdx.x;
    int r  = ty0 + (lane >> 3);
    int cc = tx0 + (lane & 7);

    float im = img[bc * (HH * WW) + r * WW + cc];
    float c  = 1.0f;
    const unsigned* lst = lists + (size_t)blk * CAP;
    const float*    ds  = pd + (size_t)bc * ((size_t)NEV * 49);
    int cnt = (int)counts[blk];
    int vOff = (r * 7 + cc) * 4;   // per-lane byte offset base 4*(7r+cc)

    for (int i = 0; i < cnt; i += 8) {
        unsigned eu[8];
        float    dv[8];
#pragma unroll
        for (int j = 0; j < 8; ++j)
            eu[j] = (unsigned)__builtin_amdgcn_readfirstlane((int)lst[i + j]);
#pragma unroll
        for (int j = 0; j < 8; ++j) {
            unsigned u = eu[j];                       // SGPR
            int t    = (int)(u & 16383u);             // SALU decode
            int x_i  = (int)((u >> 14) & 255u);
            int y_i  = (int)((u >> 22) & 255u);
            int sOff = (y_i * 7 + x_i) * 4;           // SALU
            const char* dsb = (const char*)(ds + (size_t)t * 49);  // SGPR base
            int boc = min(max(vOff - sOff, 0), 192);  // v_sub + clamp
            dv[j] = *(const float*)(dsb + boc);       // global_load v,off,s[base]
        }
#pragma unroll
        for (int j = 0; j < 8; ++j) {
            unsigned u = eu[j];
            int x_i = (int)((u >> 14) & 255u);
            int y_i = (int)((u >> 22) & 255u);
            int dr = r - y_i, dc = cc - x_i;
            bool h = (u & (1u << 30)) && (((unsigned)dr <= 6u) & ((unsigned)dc <= 6u));
            float nim = fmaf(im, c, dv[j]) * __builtin_amdgcn_rcpf(c + 1.0f);
            im = h ? nim : im;          // image update reads pre-increment count
            int er = r - x_i, ec = cc - y_i;
            bool hc = (u >> 31) && (((unsigned)er <= 6u) & ((unsigned)ec <= 6u));
            c += hc ? 1.0f : 0.0f;      // counter at transposed slice (source bug)
        }
    }
    out[bc * (HH * WW) + r * WW + cc] = im;
}

extern "C" void kernel_launch(void* const* d_in, const int* in_sizes, int n_in,
                              void* d_out, int out_size, void* d_ws, size_t ws_size,
                              hipStream_t stream) {
    const float* img = (const float*)d_in[0];
    const float* Wp  = (const float*)d_in[1];
    const float* bp  = (const float*)d_in[2];
    const float* pe  = (const float*)d_in[3];
    const float* Wb  = (const float*)d_in[4];
    const float* bb  = (const float*)d_in[5];
    float* out = (float*)d_out;

    float* wsf = (float*)d_ws;
    float*    M   = wsf;                        // 2401 floats (pad to 2404)
    float*    K   = wsf + 2404;                 // 490  floats (pad to 492)
    unsigned* xy  = (unsigned*)(wsf + 2896);    // 414720 u32
    float*    pd  = wsf + 2896 + NTASK;         // 20,321,280 floats
    unsigned* lists  = (unsigned*)(pd + (size_t)NTASK * 49);   // 12800*CAP u32 (26.2 MB)
    unsigned* counts = lists + (size_t)BCN * NTILE * CAP;      // 12800 u32

    k_mk<<<12, 256, 0, stream>>>(Wp, bp, pe, Wb, bb, M, K);
    k_sim<<<BCN * PPOS, 64, 0, stream>>>(img, xy, pd);
    k_den<<<NTASK / 256, 256, 0, stream>>>(pd, M, K);
    k_build<<<BCN * NTILE, 64, 0, stream>>>(xy, lists, counts);
    k_apply<<<BCN * NTILE, 64, 0, stream>>>(img, lists, counts, pd, out);
}

// Round 8
// 353.601 us; speedup vs baseline: 2.7622x; 1.4228x over previous
//
#include <hip/hip_runtime.h>

#define PS 7
#define NP 10
#define WIN 20
#define STR 4
#define LL 14          // WIN - PS + 1
#define HALF 7
#define HH 160
#define WW 160
#define BCN 32         // B*C
#define NX 36          // positions per axis
#define PPOS 1296      // NX*NX
#define EMBD 128
#define NTASK (BCN * PPOS * NP)   // 414720
#define NEV (PPOS * NP)           // 12960 events per plane
#define CAP 512                   // per-tile event list capacity (8x8 tiles)
#define NTILE 400                 // 20x20 tiles of 8x8 per plane

// ---------------- phase 0: M = Wp@Wb, K[n] = (bp+pos_emb[n])@Wb + bb ---------
__global__ __launch_bounds__(256) void k_mk(const float* __restrict__ Wp,
                                            const float* __restrict__ bp,
                                            const float* __restrict__ pe,
                                            const float* __restrict__ Wb,
                                            const float* __restrict__ bb,
                                            float* __restrict__ M,
                                            float* __restrict__ K) {
    int t = blockIdx.x * 256 + threadIdx.x;
    if (t < 49 * 49) {
        int k = t / 49, d = t % 49;
        float acc = 0.f;
        for (int e = 0; e < EMBD; ++e) acc += Wp[k * EMBD + e] * Wb[e * 49 + d];
        M[t] = acc;
    } else if (t < 49 * 49 + NP * 49) {
        int u = t - 49 * 49;
        int n = u / 49, d = u % 49;
        float acc = bb[d];
        for (int e = 0; e < EMBD; ++e) acc += (bp[e] + pe[n * EMBD + e]) * Wb[e * 49 + d];
        K[u] = acc;
    }
}

// ---------------- phase 1: sim + top-10 + patch extraction (round-4 proven) --
// one wave per (pos, bc). layout: t = (bc*PPOS + pos)*NP + n
__global__ __launch_bounds__(64) void k_sim(const float* __restrict__ img,
                                            unsigned* __restrict__ xy,
                                            float* __restrict__ pd) {
    int blk = blockIdx.x;
    int pos = blk % PPOS;
    int bc  = blk / PPOS;
    int lane = threadIdx.x;
    int ix = pos / NX, iy = pos % NX;
    int x = ix * STR, y = iy * STR;
    int xb0 = max(x - HALF, 0), yb0 = max(y - HALF, 0);
    int jmax = x + 6 - xb0;   // valid j <= jmax  (==13 when x>=7)
    int imax = y + 6 - yb0;
    const float* plane = img + bc * (HH * WW);

    float v[4];
    int   qi[4];
#pragma unroll
    for (int s = 0; s < 4; ++s) {
        int q = lane + s * 64;
        qi[s] = q;
        float acc = -INFINITY;
        if (q < 196) {
            int i = q / 14, j = q % 14;
            const float* wbase = plane + (yb0 + i) * WW + (xb0 + j);
            float a2 = 0.f;
#pragma unroll
            for (int a = 0; a < PS; ++a)
#pragma unroll
                for (int b = 0; b < PS; ++b)
                    a2 += wbase[a * WW + b] * plane[(y + a) * WW + (x + b)];
            acc = (i > imax || j > jmax) ? -INFINITY : a2;
        }
        v[s] = acc;
    }

    int tbase = (bc * PPOS + pos) * NP;
    for (int n = 0; n < NP; ++n) {
        // local best (value desc, index asc)
        float bv = v[0]; int bi = qi[0];
#pragma unroll
        for (int s = 1; s < 4; ++s)
            if (v[s] > bv || (v[s] == bv && qi[s] < bi)) { bv = v[s]; bi = qi[s]; }
        // wave butterfly argmax — associative lexicographic max on (val, -idx)
#pragma unroll
        for (int off = 32; off >= 1; off >>= 1) {
            float ov = __shfl_xor(bv, off);
            int   oi = __shfl_xor(bi, off);
            if (ov > bv || (ov == bv && oi < bi)) { bv = ov; bi = oi; }
        }
        // remove winner
#pragma unroll
        for (int s = 0; s < 4; ++s)
            if (qi[s] == bi) v[s] = -INFINITY;

        int oy = bi / 14, ox = bi % 14;
        int x_i = oy + xb0;        // source bug kept: col start = row off + xb0
        int y_i = ox + yb0;        // row start = col off + yb0
        int row0 = yb0 + oy, col0 = xb0 + ox;
        int t = tbase + n;
        if (lane == 0) xy[t] = (unsigned)x_i | ((unsigned)y_i << 8);
        if (lane < 49) {
            int a = lane / 7, b = lane % 7;     // patch[a*7+b] = win[oy+b][ox+a]
            pd[(size_t)t * 49 + lane] = plane[(row0 + b) * WW + (col0 + a)];
        }
    }
}

// ---------------- phase 2: den = patches @ M + K[n]  (in-place over pd) ------
__global__ __launch_bounds__(256) void k_den(float* __restrict__ pd,
                                             const float* __restrict__ Mg,
                                             const float* __restrict__ Kg) {
    __shared__ float Ps[256 * 49];
    int tid = threadIdx.x;
    size_t base = (size_t)blockIdx.x * (256 * 49);
    for (int i = tid; i < 256 * 49; i += 256) Ps[i] = pd[base + i];
    __syncthreads();

    int t = blockIdx.x * 256 + tid;
    int n = t % NP;
    float acc[49];
#pragma unroll
    for (int d = 0; d < 49; ++d) acc[d] = Kg[n * 49 + d];
    for (int k = 0; k < 49; ++k) {
        float p = Ps[tid * 49 + k];
        const float* mrow = Mg + k * 49;   // wave-uniform -> scalar loads
#pragma unroll
        for (int d = 0; d < 49; ++d) acc[d] += p * mrow[d];
    }
    __syncthreads();
#pragma unroll
    for (int d = 0; d < 49; ++d) Ps[tid * 49 + d] = acc[d];
    __syncthreads();
    for (int i = tid; i < 256 * 49; i += 256) pd[base + i] = Ps[i];
}

// ---------------- phase 3a: per-tile (8x8) event-list build ------------------
// Interval-restricted scan. x_i ∈ [xb0, xb0+13], xb0 = max(4*ix-7, 0), so
// relevance of ix to cols [t, t+7] requires xb0 <= t+7 and xb0+13 >= t-6:
//   upper: ix <= (t+14)>>2
//   lower: 0 if t <= 19 (clamp region: xb0(0)=xb0(1)=0), else ceil((t-12)/4)
// (round-7 bug: lower bound excluded ix=0 at t=16). Candidates: U×U,
// U = I(tx0) ∪ I(ty0); ascending (ix,iy) == chronological order.
__global__ __launch_bounds__(64) void k_build(const unsigned* __restrict__ xy,
                                              unsigned* __restrict__ lists,
                                              unsigned* __restrict__ counts) {
    int blk  = blockIdx.x;
    int bc   = blk / NTILE;
    int tile = blk % NTILE;
    int tx0 = (tile % 20) * 8, ty0 = (tile / 20) * 8;
    int tx1 = tx0 + 7, ty1 = ty0 + 7;
    int lane = threadIdx.x;
    const unsigned* xs = xy + bc * NEV;
    unsigned* lst = lists + (size_t)blk * CAP;

    // I(tx0) and I(ty0) — exact bounds incl. the xb0-clamp region
    int a0 = (tx0 <= 19) ? 0 : ((tx0 - 9) >> 2), a1 = min(35, (tx0 + 14) >> 2);
    int b0 = (ty0 <= 19) ? 0 : ((ty0 - 9) >> 2), b1 = min(35, (ty0 + 14) >> 2);
    if (a0 > b0) { int t0 = a0; a0 = b0; b0 = t0; int t1 = a1; a1 = b1; b1 = t1; }
    int lo0 = a0, lo1 = 0, len0, len1;
    if (b0 <= a1 + 1) { len0 = max(a1, b1) - lo0 + 1; len1 = 0; }
    else              { len0 = a1 - a0 + 1; lo1 = b0; len1 = b1 - b0 + 1; }
    int nU = len0 + len1;                    // <= 14
    unsigned m = 65536u / (unsigned)nU + 1u; // exact fastdiv (k < 4681, nU <= 14)
    int npos = nU * nU;

    unsigned cnt = 0;
    for (int base = 0; base < npos; base += 64) {
        int k = base + lane;
        bool valid = k < npos;
        unsigned kk = valid ? (unsigned)k : 0u;
        int ki = (int)((kk * m) >> 16);
        int kj = (int)kk - ki * nU;
        int ix = (ki < len0) ? (lo0 + ki) : (lo1 + ki - len0);
        int iy = (kj < len0) ? (lo0 + kj) : (lo1 + kj - len0);
        int pos = ix * NX + iy;
        const unsigned* ep = xs + pos * NP;

        unsigned ev[NP];
#pragma unroll
        for (int n = 0; n < NP; ++n) ev[n] = ep[n];

        unsigned rel = 0;
        unsigned pk[NP];
#pragma unroll
        for (int n = 0; n < NP; ++n) {
            unsigned u = ev[n];
            int x_i = (int)(u & 255u);
            int y_i = (int)((u >> 8) & 255u);
            bool ih = (x_i <= tx1) && (x_i + 6 >= tx0) &&
                      (y_i <= ty1) && (y_i + 6 >= ty0);
            bool ch = (x_i <= ty1) && (x_i + 6 >= ty0) &&
                      (y_i <= tx1) && (y_i + 6 >= tx0);
            bool any = valid && (ih || ch);
            rel |= any ? (1u << n) : 0u;
            pk[n] = (unsigned)(pos * NP + n) | ((unsigned)x_i << 14) | ((unsigned)y_i << 22)
                  | (ih ? (1u << 30) : 0u) | (ch ? (1u << 31) : 0u);
        }
        int myc = __popc(rel);
        int scan = myc;
#pragma unroll
        for (int off = 1; off < 64; off <<= 1) {
            int o = __shfl_up(scan, off);
            scan += (lane >= off) ? o : 0;
        }
        int excl  = (int)cnt + scan - myc;
        int total = __shfl(scan, 63);
        int w = excl;
#pragma unroll
        for (int n = 0; n < NP; ++n) {
            if ((rel >> n) & 1u) { if (w < CAP) lst[w] = pk[n]; ++w; }
        }
        cnt += (unsigned)total;
    }
    if (cnt > CAP) cnt = CAP;
    unsigned cntp = (cnt + 7u) & ~7u;
    if (cntp > CAP) cntp = CAP;
    if (lane < (int)(cntp - cnt)) lst[cnt + lane] = 0u;   // zero-pad (no-op events)
    if (lane == 0) counts[blk] = cntp;
}

// ---------------- phase 3b: replay compact list, one WAVE per 8x8 tile -------
// Round-4 proven inner loop verbatim (batch-of-8, scalarized decode, pure
// predication, NO branches).
__global__ __launch_bounds__(64) void k_apply(const float* __restrict__ img,
                                              const unsigned* __restrict__ lists,
                                              const unsigned* __restrict__ counts,
                                              const float* __restrict__ pd,
                                              float* __restrict__ out) {
    int blk  = blockIdx.x;
    int bc   = blk / NTILE;
    int tile = blk % NTILE;
    int tx0 = (tile % 20) * 8, ty0 = (tile / 20) * 8;
    int lane = threadIdx.x;
    int r  = ty0 + (lane >> 3);
    int cc = tx0 + (lane & 7);

    float im = img[bc * (HH * WW) + r * WW + cc];
    float c  = 1.0f;
    const unsigned* lst = lists + (size_t)blk * CAP;
    const float*    ds  = pd + (size_t)bc * ((size_t)NEV * 49);
    int cnt = (int)counts[blk];
    int vOff = (r * 7 + cc) * 4;   // per-lane byte offset base 4*(7r+cc)

    for (int i = 0; i < cnt; i += 8) {
        unsigned eu[8];
        float    dv[8];
#pragma unroll
        for (int j = 0; j < 8; ++j)
            eu[j] = (unsigned)__builtin_amdgcn_readfirstlane((int)lst[i + j]);
#pragma unroll
        for (int j = 0; j < 8; ++j) {
            unsigned u = eu[j];                       // SGPR
            int t    = (int)(u & 16383u);             // SALU decode
            int x_i  = (int)((u >> 14) & 255u);
            int y_i  = (int)((u >> 22) & 255u);
            int sOff = (y_i * 7 + x_i) * 4;           // SALU
            const char* dsb = (const char*)(ds + (size_t)t * 49);  // SGPR base
            int boc = min(max(vOff - sOff, 0), 192);  // v_sub + clamp
            dv[j] = *(const float*)(dsb + boc);       // global_load v,off,s[base]
        }
#pragma unroll
        for (int j = 0; j < 8; ++j) {
            unsigned u = eu[j];
            int x_i = (int)((u >> 14) & 255u);
            int y_i = (int)((u >> 22) & 255u);
            int dr = r - y_i, dc = cc - x_i;
            bool h = (u & (1u << 30)) && (((unsigned)dr <= 6u) & ((unsigned)dc <= 6u));
            float nim = fmaf(im, c, dv[j]) * __builtin_amdgcn_rcpf(c + 1.0f);
            im = h ? nim : im;          // image update reads pre-increment count
            int er = r - x_i, ec = cc - y_i;
            bool hc = (u >> 31) && (((unsigned)er <= 6u) & ((unsigned)ec <= 6u));
            c += hc ? 1.0f : 0.0f;      // counter at transposed slice (source bug)
        }
    }
    out[bc * (HH * WW) + r * WW + cc] = im;
}

extern "C" void kernel_launch(void* const* d_in, const int* in_sizes, int n_in,
                              void* d_out, int out_size, void* d_ws, size_t ws_size,
                              hipStream_t stream) {
    const float* img = (const float*)d_in[0];
    const float* Wp  = (const float*)d_in[1];
    const float* bp  = (const float*)d_in[2];
    const float* pe  = (const float*)d_in[3];
    const float* Wb  = (const float*)d_in[4];
    const float* bb  = (const float*)d_in[5];
    float* out = (float*)d_out;

    float* wsf = (float*)d_ws;
    float*    M   = wsf;                        // 2401 floats (pad to 2404)
    float*    K   = wsf + 2404;                 // 490  floats (pad to 492)
    unsigned* xy  = (unsigned*)(wsf + 2896);    // 414720 u32
    float*    pd  = wsf + 2896 + NTASK;         // 20,321,280 floats
    unsigned* lists  = (unsigned*)(pd + (size_t)NTASK * 49);   // 12800*CAP u32 (26.2 MB)
    unsigned* counts = lists + (size_t)BCN * NTILE * CAP;      // 12800 u32

    k_mk<<<12, 256, 0, stream>>>(Wp, bp, pe, Wb, bb, M, K);
    k_sim<<<BCN * PPOS, 64, 0, stream>>>(img, xy, pd);
    k_den<<<NTASK / 256, 256, 0, stream>>>(pd, M, K);
    k_build<<<BCN * NTILE, 64, 0, stream>>>(xy, lists, counts);
    k_apply<<<BCN * NTILE, 64, 0, stream>>>(img, lists, counts, pd, out);
}